// Round 1
// baseline (212.525 us; speedup 1.0000x reference)
//
#include <hip/hip_runtime.h>
#include <hip/hip_bf16.h>
#include <stdint.h>

typedef __bf16 bf16;
typedef __bf16 bf16x8 __attribute__((ext_vector_type(8)));
typedef float f32x4 __attribute__((ext_vector_type(4)));

#define BM 128
#define BN 128
#define BK 64
#define LDS_STRIDE 72  // BK + 8 pad: row stride 144B -> 2-way LDS bank aliasing (free)

// ---- weight prep: fp32 [K,N] -> bf16 W^T [N,K] ----
__global__ __launch_bounds__(256) void transpose_w(const float* __restrict__ W, bf16* __restrict__ WT,
                                                   int shiftK, int N, int total) {
  int id = blockIdx.x * 256 + threadIdx.x;
  if (id >= total) return;
  int K = 1 << shiftK;
  int n = id >> shiftK;
  int k = id & (K - 1);
  WT[id] = (bf16)W[(size_t)k * N + n];
}

__global__ __launch_bounds__(256) void make_bias(const float* __restrict__ bp, const float* __restrict__ bl,
                                                 float* __restrict__ out) {
  int i = blockIdx.x * 256 + threadIdx.x;
  if (i < 128) out[i] = bp[i];
  else if (i < 384) out[i] = bl[i - 128];
}

// ---- generic 128x128 bf16 MFMA GEMM, C = relu(A @ B^T_rowmajor + bias) ----
// ASRC: 0 = A bf16 [M,K]; 1 = A fp32 [M,K] (converted in staging); 2 = virtual concat [g | loc]
// POOL: kernel-1 mode. n-tile 0 computes x1=relu(obs@W_pre+b) and writes only the
//       16-row (per-sample) mean to pool_out; other n-tiles write loc at col n0-128.
template <int ASRC, bool POOL>
__global__ __launch_bounds__(256) void gemm_k(
    const float* __restrict__ Af, const bf16* __restrict__ Ab, const bf16* __restrict__ Ag,
    const bf16* __restrict__ BT, const float* __restrict__ bias,
    bf16* __restrict__ C, int ldc, bf16* __restrict__ pool_out,
    int M, int K) {
  __shared__ bf16 As[BM * LDS_STRIDE];
  __shared__ bf16 Bs[BN * LDS_STRIDE];

  const int tid = threadIdx.x;
  const int m0 = blockIdx.y * BM;
  const int n0 = blockIdx.x * BN;

  f32x4 acc[4][4] = {};

  const int lane = tid & 63;
  const int wave = tid >> 6;
  const int wm = (wave >> 1) * 64;   // wave row offset
  const int wn = (wave & 1) * 64;    // wave col offset
  const int lm = lane & 15;
  const int quad = lane >> 4;

  for (int k0 = 0; k0 < K; k0 += BK) {
    // ---- stage A tile [128 x 64] and B tile [128n x 64k] into LDS ----
#pragma unroll
    for (int it = 0; it < 4; it++) {
      int idx = tid + it * 256;       // 1024 slots of 8 bf16
      int row = idx >> 3;
      int cv = (idx & 7) * 8;
      bf16x8 v;
      if (ASRC == 1) {
        const float* src = Af + (size_t)(m0 + row) * K + k0 + cv;
        float4 f0 = *(const float4*)src;
        float4 f1 = *(const float4*)(src + 4);
        v[0] = (bf16)f0.x; v[1] = (bf16)f0.y; v[2] = (bf16)f0.z; v[3] = (bf16)f0.w;
        v[4] = (bf16)f1.x; v[5] = (bf16)f1.y; v[6] = (bf16)f1.z; v[7] = (bf16)f1.w;
      } else if (ASRC == 0) {
        v = *(const bf16x8*)(Ab + (size_t)(m0 + row) * K + k0 + cv);
      } else {
        int r = m0 + row;
        const bf16* src = (k0 < 256) ? (Ag + (size_t)(r >> 4) * 256 + k0 + cv)
                                     : (Ab + (size_t)r * 256 + (k0 - 256) + cv);
        v = *(const bf16x8*)src;
      }
      *(bf16x8*)&As[row * LDS_STRIDE + cv] = v;

      bf16x8 w = *(const bf16x8*)(BT + (size_t)(n0 + row) * K + k0 + cv);
      *(bf16x8*)&Bs[row * LDS_STRIDE + cv] = w;
    }
    __syncthreads();

    const bf16* aBase = &As[(wm + lm) * LDS_STRIDE + quad * 8];
    const bf16* bBase = &Bs[(wn + lm) * LDS_STRIDE + quad * 8];
#pragma unroll
    for (int kk = 0; kk < BK; kk += 32) {
      bf16x8 a[4], b[4];
#pragma unroll
      for (int i = 0; i < 4; i++) a[i] = *(const bf16x8*)(aBase + i * 16 * LDS_STRIDE + kk);
#pragma unroll
      for (int j = 0; j < 4; j++) b[j] = *(const bf16x8*)(bBase + j * 16 * LDS_STRIDE + kk);
#pragma unroll
      for (int i = 0; i < 4; i++)
#pragma unroll
        for (int j = 0; j < 4; j++)
          acc[i][j] = __builtin_amdgcn_mfma_f32_16x16x32_bf16(a[i], b[j], acc[i][j], 0, 0, 0);
    }
    __syncthreads();
  }

  // ---- epilogue ----
  if (POOL && n0 == 0) {
    // each 16x16 frag covers exactly one sample's 16 nodes; mean over rows -> xbar
#pragma unroll
    for (int i = 0; i < 4; i++) {
      int sample = (m0 + wm + i * 16) >> 4;
#pragma unroll
      for (int j = 0; j < 4; j++) {
        int col = wn + j * 16 + lm;
        float b = bias[col];
        float s = 0.f;
#pragma unroll
        for (int r = 0; r < 4; r++) s += fmaxf(acc[i][j][r] + b, 0.f);
        s += __shfl_xor(s, 16);
        s += __shfl_xor(s, 32);
        if (quad == 0) pool_out[(size_t)sample * 128 + col] = (bf16)(s * 0.0625f);
      }
    }
  } else {
    const int coff = POOL ? (n0 - 128) : n0;
#pragma unroll
    for (int i = 0; i < 4; i++)
#pragma unroll
      for (int j = 0; j < 4; j++) {
        int gcol = n0 + wn + j * 16 + lm;
        float b = bias[gcol];
        int col = coff + wn + j * 16 + lm;
#pragma unroll
        for (int r = 0; r < 4; r++) {
          int row = m0 + wm + i * 16 + quad * 4 + r;
          float v = fmaxf(acc[i][j][r] + b, 0.f);
          C[(size_t)row * ldc + col] = (bf16)v;
        }
      }
  }
}

// ---- W3 head: q = z2 @ W3 + b3, N=8, memory-bound. W3 held in registers. ----
__global__ __launch_bounds__(256) void qhead(const bf16* __restrict__ z2, const float* __restrict__ W3,
                                             const float* __restrict__ b3, float* __restrict__ out, int M) {
  int tid = threadIdx.x;
  int lane = tid & 63;
  int wave = tid >> 6;
  int n = lane & 7;            // output column for this lane
  int ks = (lane >> 3) * 64;   // k-slice
  float w[64];
#pragma unroll
  for (int i = 0; i < 64; i++) w[i] = W3[(size_t)(ks + i) * 8 + n];
  float bn = b3[n];
  int gw = blockIdx.x * 4 + wave;
  int stride = gridDim.x * 4;
  for (int row = gw; row < M; row += stride) {
    const bf16* zr = z2 + (size_t)row * 512 + ks;
    float acc = 0.f;
#pragma unroll
    for (int jj = 0; jj < 8; jj++) {
      bf16x8 zv = *(const bf16x8*)(zr + jj * 8);
#pragma unroll
      for (int i = 0; i < 8; i++) acc += (float)zv[i] * w[jj * 8 + i];
    }
    acc += __shfl_down(acc, 32);
    acc += __shfl_down(acc, 16);
    acc += __shfl_down(acc, 8);
    if (lane < 8) out[(size_t)row * 8 + lane] = acc + bn;
  }
}

extern "C" void kernel_launch(void* const* d_in, const int* in_sizes, int n_in,
                              void* d_out, int out_size, void* d_ws, size_t ws_size,
                              hipStream_t stream) {
  const float* obs    = (const float*)d_in[0];
  const float* W_pre  = (const float*)d_in[1];
  const float* b_pre  = (const float*)d_in[2];
  const float* W_gcn  = (const float*)d_in[3];
  const float* b_gcn  = (const float*)d_in[4];
  const float* W_post = (const float*)d_in[5];
  const float* b_post = (const float*)d_in[6];
  const float* W_loc  = (const float*)d_in[7];
  const float* b_loc  = (const float*)d_in[8];
  const float* W1     = (const float*)d_in[9];
  const float* b1     = (const float*)d_in[10];
  const float* W2     = (const float*)d_in[11];
  const float* b2     = (const float*)d_in[12];
  const float* W3     = (const float*)d_in[13];
  const float* b3     = (const float*)d_in[14];
  float* out = (float*)d_out;

  char* p = (char*)d_ws;
  auto alloc = [&](size_t bytes) { char* r = p; p += (bytes + 255) & ~(size_t)255; return r; };
  bf16* WpreLocT = (bf16*)alloc(384 * 128 * 2);   // [384n x 128k]: rows 0..127 W_pre^T, 128..383 W_loc^T
  float* biasPL  = (float*)alloc(384 * 4);
  bf16* Wg0T   = (bf16*)alloc(128 * 128 * 2);
  bf16* Wg1T   = (bf16*)alloc(128 * 128 * 2);
  bf16* WpostT = (bf16*)alloc(256 * 128 * 2);
  bf16* W1T    = (bf16*)alloc(512 * 512 * 2);
  bf16* W2T    = (bf16*)alloc(512 * 512 * 2);
  bf16* xbar   = (bf16*)alloc(2048 * 128 * 2);            // per-sample mean of relu(obs@W_pre+b)
  bf16* loc    = (bf16*)alloc((size_t)32768 * 256 * 2);   // relu(obs@W_loc+b)
  bf16* x2     = (bf16*)alloc(2048 * 128 * 2);
  bf16* x3     = (bf16*)alloc(2048 * 128 * 2);
  bf16* g      = (bf16*)alloc(2048 * 256 * 2);
  bf16* z1     = (bf16*)alloc((size_t)32768 * 512 * 2);
  bf16* z2     = (bf16*)alloc((size_t)32768 * 512 * 2);

  // weight prep (bf16, transposed)
  transpose_w<<<64, 256, 0, stream>>>(W_pre, WpreLocT, 7, 128, 128 * 128);
  transpose_w<<<128, 256, 0, stream>>>(W_loc, WpreLocT + 128 * 128, 7, 256, 256 * 128);
  transpose_w<<<64, 256, 0, stream>>>(W_gcn, Wg0T, 7, 128, 128 * 128);
  transpose_w<<<64, 256, 0, stream>>>(W_gcn + 128 * 128, Wg1T, 7, 128, 128 * 128);
  transpose_w<<<128, 256, 0, stream>>>(W_post, WpostT, 7, 256, 256 * 128);
  transpose_w<<<1024, 256, 0, stream>>>(W1, W1T, 9, 512, 512 * 512);
  transpose_w<<<1024, 256, 0, stream>>>(W2, W2T, 9, 512, 512 * 512);
  make_bias<<<2, 256, 0, stream>>>(b_pre, b_loc, biasPL);

  // K1: fused pre (with per-sample pooling -> xbar) + loc. N = 384 (128 pre | 256 loc)
  gemm_k<1, true><<<dim3(3, 256), 256, 0, stream>>>(obs, nullptr, nullptr, WpreLocT, biasPL,
                                                    loc, 256, xbar, 32768, 128);
  // K2: collapsed GCN chain on 2048 rows (all nodes of a sample are identical after layer 1)
  gemm_k<0, false><<<dim3(1, 16), 256, 0, stream>>>(nullptr, xbar, nullptr, Wg0T, b_gcn,
                                                    x2, 128, nullptr, 2048, 128);
  gemm_k<0, false><<<dim3(1, 16), 256, 0, stream>>>(nullptr, x2, nullptr, Wg1T, b_gcn + 128,
                                                    x3, 128, nullptr, 2048, 128);
  gemm_k<0, false><<<dim3(2, 16), 256, 0, stream>>>(nullptr, x3, nullptr, WpostT, b_post,
                                                    g, 256, nullptr, 2048, 128);
  // K3: z1 = relu([g repeated | loc] @ W1 + b1)   (concat virtualized in staging)
  gemm_k<2, false><<<dim3(4, 256), 256, 0, stream>>>(nullptr, loc, g, W1T, b1,
                                                     z1, 512, nullptr, 32768, 512);
  // K4: z2 = relu(z1 @ W2 + b2)
  gemm_k<0, false><<<dim3(4, 256), 256, 0, stream>>>(nullptr, z1, nullptr, W2T, b2,
                                                     z2, 512, nullptr, 32768, 512);
  // K5: q = z2 @ W3 + b3 (fp32 out)
  qhead<<<1024, 256, 0, stream>>>(z2, W3, b3, out, 32768);
}

// Round 2
// 199.643 us; speedup vs baseline: 1.0645x; 1.0645x over previous
//
#include <hip/hip_runtime.h>
#include <hip/hip_bf16.h>
#include <stdint.h>

typedef __bf16 bf16;
typedef __bf16 bf16x8 __attribute__((ext_vector_type(8)));
typedef float f32x4 __attribute__((ext_vector_type(4)));

#define BM 128
#define BN 128
#define BK 64

// global_load_lds pointer casts (AS1 global, AS3 LDS)
#define GL(p) ((const __attribute__((address_space(1))) void*)(p))
#define SH(p) ((__attribute__((address_space(3))) void*)(p))

// ---- merged weight prep: all W^T bf16 conversions + bias concat, 1 launch ----
__device__ inline void tp(const float* W, bf16* WT, int id, int shiftK, int N) {
  int K = 1 << shiftK;
  int n = id >> shiftK;
  int k = id & (K - 1);
  WT[id] = (bf16)W[(size_t)k * N + n];
}

__global__ __launch_bounds__(256) void prep_weights(
    const float* __restrict__ Wpre, const float* __restrict__ Wloc,
    const float* __restrict__ Wgcn, const float* __restrict__ Wpost,
    const float* __restrict__ W1, const float* __restrict__ W2,
    const float* __restrict__ bpre, const float* __restrict__ bloc,
    bf16* __restrict__ WpreLocT, bf16* __restrict__ Wg0T, bf16* __restrict__ Wg1T,
    bf16* __restrict__ WpostT, bf16* __restrict__ W1T, bf16* __restrict__ W2T,
    float* __restrict__ biasPL) {
  int id = blockIdx.x * 256 + threadIdx.x;
  if (id < 16384) { tp(Wpre, WpreLocT, id, 7, 128); return; } id -= 16384;
  if (id < 32768) { tp(Wloc, WpreLocT + 16384, id, 7, 256); return; } id -= 32768;
  if (id < 16384) { tp(Wgcn, Wg0T, id, 7, 128); return; } id -= 16384;
  if (id < 16384) { tp(Wgcn + 16384, Wg1T, id, 7, 128); return; } id -= 16384;
  if (id < 32768) { tp(Wpost, WpostT, id, 7, 256); return; } id -= 32768;
  if (id < 262144) { tp(W1, W1T, id, 9, 512); return; } id -= 262144;
  if (id < 262144) { tp(W2, W2T, id, 9, 512); return; } id -= 262144;
  if (id < 128) { biasPL[id] = bpre[id]; return; } id -= 128;
  if (id < 256) { biasPL[128 + id] = bloc[id]; }
}

// ---- obs fp32 -> bf16, streaming ----
__global__ __launch_bounds__(256) void obs_convert(const float* __restrict__ obs,
                                                   bf16* __restrict__ out) {
  int id = blockIdx.x * 256 + threadIdx.x;  // chunk of 8
  const float4* s = (const float4*)(obs + (size_t)id * 8);
  float4 f0 = s[0], f1 = s[1];
  bf16x8 v;
  v[0] = (bf16)f0.x; v[1] = (bf16)f0.y; v[2] = (bf16)f0.z; v[3] = (bf16)f0.w;
  v[4] = (bf16)f1.x; v[5] = (bf16)f1.y; v[6] = (bf16)f1.z; v[7] = (bf16)f1.w;
  *(bf16x8*)(out + (size_t)id * 8) = v;
}

// ---- 128x128 bf16 MFMA GEMM, C = relu(A @ B^T + bias) ----
// Staging via global_load_lds (16B/lane). LDS layout unpadded with XOR swizzle
// applied on the SOURCE address: physical chunk (row, p) holds logical unit
// p ^ (row&7), making ds_read_b128 fragment reads conflict-free.
// CONCAT: A = [g(repeat 16) | loc], both stride 256.  POOL: kernel-1 mode.
template <bool CONCAT, bool POOL>
__global__ __launch_bounds__(256) void gemm_k(
    const bf16* __restrict__ Ab, const bf16* __restrict__ Ag,
    const bf16* __restrict__ BT, const float* __restrict__ bias,
    bf16* __restrict__ C, int ldc, bf16* __restrict__ pool_out,
    int M, int K) {
  __shared__ bf16 As[BM * BK];
  __shared__ bf16 Bs[BN * BK];

  const int tid = threadIdx.x;
  const int m0 = blockIdx.y * BM;
  const int n0 = blockIdx.x * BN;

  f32x4 acc[4][4] = {};

  const int lane = tid & 63;
  const int wave = tid >> 6;
  const int wm = (wave >> 1) * 64;
  const int wn = (wave & 1) * 64;
  const int lm = lane & 15;
  const int quad = lane >> 4;

  for (int k0 = 0; k0 < K; k0 += BK) {
#pragma unroll
    for (int it = 0; it < 4; it++) {
      int idx = it * 256 + tid;                 // physical 16B chunk index
      int row = idx >> 3;
      int cv8 = (idx & 7) ^ (row & 7);          // logical k-unit (XOR swizzle)
      int kk = k0 + cv8 * 8;
      const bf16* ga;
      if (CONCAT) {
        int r = m0 + row;
        ga = (k0 < 256) ? (Ag + (size_t)(r >> 4) * 256 + kk)
                        : (Ab + (size_t)r * 256 + (kk - 256));
      } else {
        ga = Ab + (size_t)(m0 + row) * K + kk;
      }
      const bf16* gb = BT + (size_t)(n0 + row) * K + kk;
      __builtin_amdgcn_global_load_lds(GL(ga), SH(&As[(idx & ~63) * 8]), 16, 0, 0);
      __builtin_amdgcn_global_load_lds(GL(gb), SH(&Bs[(idx & ~63) * 8]), 16, 0, 0);
    }
    __syncthreads();   // compiler emits vmcnt(0) drain before s_barrier

#pragma unroll
    for (int ks = 0; ks < 2; ks++) {
      const int ua = quad + ks * 4;             // logical k-unit of this frag
      bf16x8 a[4], b[4];
#pragma unroll
      for (int i = 0; i < 4; i++) {
        int r = wm + lm + i * 16;
        a[i] = *(const bf16x8*)&As[r * 64 + ((ua ^ (r & 7)) * 8)];
      }
#pragma unroll
      for (int j = 0; j < 4; j++) {
        int r = wn + lm + j * 16;
        b[j] = *(const bf16x8*)&Bs[r * 64 + ((ua ^ (r & 7)) * 8)];
      }
#pragma unroll
      for (int i = 0; i < 4; i++)
#pragma unroll
        for (int j = 0; j < 4; j++)
          acc[i][j] = __builtin_amdgcn_mfma_f32_16x16x32_bf16(a[i], b[j], acc[i][j], 0, 0, 0);
    }
    __syncthreads();
  }

  // ---- epilogue ----
  if (POOL && n0 == 0) {
#pragma unroll
    for (int i = 0; i < 4; i++) {
      int sample = (m0 + wm + i * 16) >> 4;
#pragma unroll
      for (int j = 0; j < 4; j++) {
        int col = wn + j * 16 + lm;
        float b = bias[col];
        float s = 0.f;
#pragma unroll
        for (int r = 0; r < 4; r++) s += fmaxf(acc[i][j][r] + b, 0.f);
        s += __shfl_xor(s, 16);
        s += __shfl_xor(s, 32);
        if (quad == 0) pool_out[(size_t)sample * 128 + col] = (bf16)(s * 0.0625f);
      }
    }
  } else {
    const int coff = POOL ? (n0 - 128) : n0;
#pragma unroll
    for (int i = 0; i < 4; i++)
#pragma unroll
      for (int j = 0; j < 4; j++) {
        int gcol = n0 + wn + j * 16 + lm;
        float b = bias[gcol];
        int col = coff + wn + j * 16 + lm;
#pragma unroll
        for (int r = 0; r < 4; r++) {
          int row = m0 + wm + i * 16 + quad * 4 + r;
          float v = fmaxf(acc[i][j][r] + b, 0.f);
          C[(size_t)row * ldc + col] = (bf16)v;
        }
      }
  }
}

// ---- fused collapsed-GCN chain: xbar -> x2 -> x3 -> g (row-local across layers) ----
// 128 blocks x 16 rows; 4 waves split the N dimension; weights staged per layer.
__global__ __launch_bounds__(256) void gcn_chain(
    const bf16* __restrict__ xbar, const bf16* __restrict__ Wg0T,
    const bf16* __restrict__ Wg1T, const bf16* __restrict__ WpostT,
    const float* __restrict__ b_gcn, const float* __restrict__ b_post,
    bf16* __restrict__ g) {
  __shared__ bf16 xs[16 * 136];
  __shared__ bf16 ws[256 * 136];
  const int tid = threadIdx.x;
  const int lane = tid & 63, wave = tid >> 6;
  const int lm = lane & 15, quad = lane >> 4;
  const int rb = blockIdx.x * 16;

  {  // load 16 rows x 128 cols of xbar
    int row = tid >> 4, cv = (tid & 15) * 8;
    *(bf16x8*)&xs[row * 136 + cv] = *(const bf16x8*)&xbar[(size_t)(rb + row) * 128 + cv];
  }

  const bf16* Wl[3] = {Wg0T, Wg1T, WpostT};
  const float* bl[3] = {b_gcn, b_gcn + 128, b_post};
  const int Nl[3] = {128, 128, 256};

  for (int l = 0; l < 3; l++) {
    const int N = Nl[l];
    __syncthreads();
    for (int c = tid; c < N * 16; c += 256) {   // stage W^T [N x 128]
      int row = c >> 4, cv = (c & 15) * 8;
      *(bf16x8*)&ws[row * 136 + cv] = *(const bf16x8*)&Wl[l][(size_t)row * 128 + cv];
    }
    __syncthreads();
    const int nj = N / 64;                       // j-tiles per wave (2 or 4)
    f32x4 acc[4] = {};
#pragma unroll
    for (int kk = 0; kk < 128; kk += 32) {
      bf16x8 a = *(const bf16x8*)&xs[lm * 136 + quad * 8 + kk];
      for (int j = 0; j < nj; j++) {
        int col = (wave * nj + j) * 16 + lm;
        bf16x8 b = *(const bf16x8*)&ws[col * 136 + quad * 8 + kk];
        acc[j] = __builtin_amdgcn_mfma_f32_16x16x32_bf16(a, b, acc[j], 0, 0, 0);
      }
    }
    __syncthreads();   // all xs reads done before overwrite
    const float* bias = bl[l];
    if (l < 2) {
      for (int j = 0; j < nj; j++) {
        int col = (wave * nj + j) * 16 + lm;
        float bv = bias[col];
#pragma unroll
        for (int r = 0; r < 4; r++)
          xs[(quad * 4 + r) * 136 + col] = (bf16)fmaxf(acc[j][r] + bv, 0.f);
      }
    } else {
      for (int j = 0; j < nj; j++) {
        int col = (wave * nj + j) * 16 + lm;
        float bv = bias[col];
#pragma unroll
        for (int r = 0; r < 4; r++)
          g[(size_t)(rb + quad * 4 + r) * 256 + col] = (bf16)fmaxf(acc[j][r] + bv, 0.f);
      }
    }
  }
}

// ---- W3 head: q = z2 @ W3 + b3, N=8, memory-bound ----
__global__ __launch_bounds__(256) void qhead(const bf16* __restrict__ z2, const float* __restrict__ W3,
                                             const float* __restrict__ b3, float* __restrict__ out, int M) {
  int tid = threadIdx.x;
  int lane = tid & 63;
  int wave = tid >> 6;
  int n = lane & 7;
  int ks = (lane >> 3) * 64;
  float w[64];
#pragma unroll
  for (int i = 0; i < 64; i++) w[i] = W3[(size_t)(ks + i) * 8 + n];
  float bn = b3[n];
  int gw = blockIdx.x * 4 + wave;
  int stride = gridDim.x * 4;
  for (int row = gw; row < M; row += stride) {
    const bf16* zr = z2 + (size_t)row * 512 + ks;
    float acc = 0.f;
#pragma unroll
    for (int jj = 0; jj < 8; jj++) {
      bf16x8 zv = *(const bf16x8*)(zr + jj * 8);
#pragma unroll
      for (int i = 0; i < 8; i++) acc += (float)zv[i] * w[jj * 8 + i];
    }
    acc += __shfl_down(acc, 32);
    acc += __shfl_down(acc, 16);
    acc += __shfl_down(acc, 8);
    if (lane < 8) out[(size_t)row * 8 + lane] = acc + bn;
  }
}

extern "C" void kernel_launch(void* const* d_in, const int* in_sizes, int n_in,
                              void* d_out, int out_size, void* d_ws, size_t ws_size,
                              hipStream_t stream) {
  const float* obs    = (const float*)d_in[0];
  const float* W_pre  = (const float*)d_in[1];
  const float* b_pre  = (const float*)d_in[2];
  const float* W_gcn  = (const float*)d_in[3];
  const float* b_gcn  = (const float*)d_in[4];
  const float* W_post = (const float*)d_in[5];
  const float* b_post = (const float*)d_in[6];
  const float* W_loc  = (const float*)d_in[7];
  const float* b_loc  = (const float*)d_in[8];
  const float* W1     = (const float*)d_in[9];
  const float* b1     = (const float*)d_in[10];
  const float* W2     = (const float*)d_in[11];
  const float* b2     = (const float*)d_in[12];
  const float* W3     = (const float*)d_in[13];
  const float* b3     = (const float*)d_in[14];
  float* out = (float*)d_out;

  char* p = (char*)d_ws;
  auto alloc = [&](size_t bytes) { char* r = p; p += (bytes + 255) & ~(size_t)255; return r; };
  bf16* WpreLocT = (bf16*)alloc(384 * 128 * 2);
  float* biasPL  = (float*)alloc(384 * 4);
  bf16* Wg0T   = (bf16*)alloc(128 * 128 * 2);
  bf16* Wg1T   = (bf16*)alloc(128 * 128 * 2);
  bf16* WpostT = (bf16*)alloc(256 * 128 * 2);
  bf16* W1T    = (bf16*)alloc(512 * 512 * 2);
  bf16* W2T    = (bf16*)alloc(512 * 512 * 2);
  bf16* obs_bf = (bf16*)alloc((size_t)32768 * 128 * 2);
  bf16* xbar   = (bf16*)alloc(2048 * 128 * 2);
  bf16* loc    = (bf16*)alloc((size_t)32768 * 256 * 2);
  bf16* g      = (bf16*)alloc(2048 * 256 * 2);
  bf16* z1     = (bf16*)alloc((size_t)32768 * 512 * 2);
  bf16* z2     = (bf16*)alloc((size_t)32768 * 512 * 2);

  prep_weights<<<2498, 256, 0, stream>>>(W_pre, W_loc, W_gcn, W_post, W1, W2, b_pre, b_loc,
                                         WpreLocT, Wg0T, Wg1T, WpostT, W1T, W2T, biasPL);
  obs_convert<<<2048, 256, 0, stream>>>(obs, obs_bf);

  // K1: fused pre (pool -> xbar) + loc. N=384 (128 pre | 256 loc)
  gemm_k<false, true><<<dim3(3, 256), 256, 0, stream>>>(obs_bf, nullptr, WpreLocT, biasPL,
                                                        loc, 256, xbar, 32768, 128);
  // K2: collapsed GCN chain (one launch)
  gcn_chain<<<128, 256, 0, stream>>>(xbar, Wg0T, Wg1T, WpostT, b_gcn, b_post, g);
  // K3: z1 = relu([g | loc] @ W1 + b1)
  gemm_k<true, false><<<dim3(4, 256), 256, 0, stream>>>(loc, g, W1T, b1,
                                                        z1, 512, nullptr, 32768, 512);
  // K4: z2 = relu(z1 @ W2 + b2)
  gemm_k<false, false><<<dim3(4, 256), 256, 0, stream>>>(z1, nullptr, W2T, b2,
                                                         z2, 512, nullptr, 32768, 512);
  // K5: q = z2 @ W3 + b3
  qhead<<<1024, 256, 0, stream>>>(z2, W3, b3, out, 32768);
}

// Round 3
// 185.240 us; speedup vs baseline: 1.1473x; 1.0778x over previous
//
#include <hip/hip_runtime.h>
#include <hip/hip_bf16.h>
#include <stdint.h>

typedef __bf16 bf16;
typedef __bf16 bf16x4 __attribute__((ext_vector_type(4)));
typedef __bf16 bf16x8 __attribute__((ext_vector_type(8)));
typedef float f32x4 __attribute__((ext_vector_type(4)));

#define BM 128
#define BN 128
#define BK 64

#define GL(p) ((const __attribute__((address_space(1))) void*)(p))
#define SH(p) ((__attribute__((address_space(3))) void*)(p))

// ---- mega-prep: obs->bf16, tiled W1/W2 transpose, small transposes, bias ----
__device__ inline void tp(const float* W, bf16* WT, int id, int shiftK, int N) {
  int K = 1 << shiftK;
  int n = id >> shiftK;
  int k = id & (K - 1);
  WT[id] = (bf16)W[(size_t)k * N + n];
}

__global__ __launch_bounds__(256) void prep_all(
    const float* __restrict__ obs, bf16* __restrict__ obs_bf,
    const float* __restrict__ W1, const float* __restrict__ W2,
    bf16* __restrict__ W1T, bf16* __restrict__ W2T,
    const float* __restrict__ Wpre, const float* __restrict__ Wloc,
    const float* __restrict__ Wgcn, const float* __restrict__ Wpost,
    bf16* __restrict__ WpreLocT, bf16* __restrict__ Wg0T, bf16* __restrict__ Wg1T,
    bf16* __restrict__ WpostT,
    const float* __restrict__ bpre, const float* __restrict__ bloc,
    float* __restrict__ biasPL) {
  __shared__ bf16 tile[64 * 68];
  int blk = blockIdx.x;
  int tid = threadIdx.x;
  if (blk < 2048) {                      // obs fp32 -> bf16 (4.19M elems)
    int id = blk * 256 + tid;
    const float4* s = (const float4*)(obs + (size_t)id * 8);
    float4 f0 = s[0], f1 = s[1];
    bf16x8 v;
    v[0] = (bf16)f0.x; v[1] = (bf16)f0.y; v[2] = (bf16)f0.z; v[3] = (bf16)f0.w;
    v[4] = (bf16)f1.x; v[5] = (bf16)f1.y; v[6] = (bf16)f1.z; v[7] = (bf16)f1.w;
    *(bf16x8*)(obs_bf + (size_t)id * 8) = v;
    return;
  }
  blk -= 2048;
  if (blk < 128) {                       // tiled transpose W1/W2 (512x512 each, 64 tiles)
    const float* W = (blk < 64) ? W1 : W2;
    bf16* WT = (blk < 64) ? W1T : W2T;
    int t = blk & 63;
    int tk0 = (t >> 3) * 64, tn0 = (t & 7) * 64;
#pragma unroll
    for (int p = 0; p < 4; p++) {
      int kr = p * 16 + (tid >> 4), nc = (tid & 15) * 4;
      float4 f = *(const float4*)(W + (size_t)(tk0 + kr) * 512 + tn0 + nc);
      bf16x4 v; v[0] = (bf16)f.x; v[1] = (bf16)f.y; v[2] = (bf16)f.z; v[3] = (bf16)f.w;
      *(bf16x4*)&tile[kr * 68 + nc] = v;
    }
    __syncthreads();
#pragma unroll
    for (int p = 0; p < 4; p++) {
      int nr = p * 16 + (tid >> 4), kc = (tid & 15) * 4;
      bf16x4 v;
#pragma unroll
      for (int i = 0; i < 4; i++) v[i] = tile[(kc + i) * 68 + nr];
      *(bf16x4*)(WT + (size_t)(tn0 + nr) * 512 + tk0 + kc) = v;
    }
    return;
  }
  blk -= 128;
  if (blk < 448) {                       // small transposes (114688 elems)
    int id = blk * 256 + tid;
    if (id < 16384) { tp(Wpre, WpreLocT, id, 7, 128); return; } id -= 16384;
    if (id < 32768) { tp(Wloc, WpreLocT + 16384, id, 7, 256); return; } id -= 32768;
    if (id < 16384) { tp(Wgcn, Wg0T, id, 7, 128); return; } id -= 16384;
    if (id < 16384) { tp(Wgcn + 16384, Wg1T, id, 7, 128); return; } id -= 16384;
    tp(Wpost, WpostT, id, 7, 256);
    return;
  }
  // bias concat
  if (tid < 128) biasPL[tid] = bpre[tid];
  biasPL[128 + tid] = bloc[tid];
}

// ---- 128x128 bf16 MFMA GEMM, C = relu(A @ B^T + bias) ----
// global_load_lds staging (16B/lane), XOR-swizzled source so unpadded LDS is
// conflict-free for ds_read_b128 fragments.
// CONCAT: A = [g(repeat16) | loc].  POOL: K1 mode (n-tile 0 -> pooled xbar).
// QFUSE: K4 mode - no C store; z2 tile -> LDS -> q partial (tile n-slice of W3).
template <bool CONCAT, bool POOL, bool QFUSE, int WPE>
__global__ __launch_bounds__(256, WPE) void gemm_k(
    const bf16* __restrict__ Ab, const bf16* __restrict__ Ag,
    const bf16* __restrict__ BT, const float* __restrict__ bias,
    bf16* __restrict__ C, int ldc, bf16* __restrict__ pool_out,
    const float* __restrict__ W3, float* __restrict__ qpart,
    int M, int K) {
  __shared__ bf16 smem[16384];
  bf16* As = smem;
  bf16* Bs = smem + 8192;

  const int tid = threadIdx.x;
  const int m0 = blockIdx.y * BM;
  const int n0 = blockIdx.x * BN;

  f32x4 acc[4][4] = {};

  const int lane = tid & 63;
  const int wave = tid >> 6;
  const int wm = (wave >> 1) * 64;
  const int wn = (wave & 1) * 64;
  const int lm = lane & 15;
  const int quad = lane >> 4;

  for (int k0 = 0; k0 < K; k0 += BK) {
#pragma unroll
    for (int it = 0; it < 4; it++) {
      int idx = it * 256 + tid;
      int row = idx >> 3;
      int cv8 = (idx & 7) ^ (row & 7);
      int kk = k0 + cv8 * 8;
      const bf16* ga;
      if (CONCAT) {
        int r = m0 + row;
        ga = (k0 < 256) ? (Ag + (size_t)(r >> 4) * 256 + kk)
                        : (Ab + (size_t)r * 256 + (kk - 256));
      } else {
        ga = Ab + (size_t)(m0 + row) * K + kk;
      }
      const bf16* gb = BT + (size_t)(n0 + row) * K + kk;
      __builtin_amdgcn_global_load_lds(GL(ga), SH(&As[(idx & ~63) * 8]), 16, 0, 0);
      __builtin_amdgcn_global_load_lds(GL(gb), SH(&Bs[(idx & ~63) * 8]), 16, 0, 0);
    }
    __syncthreads();

#pragma unroll
    for (int ks = 0; ks < 2; ks++) {
      const int ua = quad + ks * 4;
      bf16x8 a[4], b[4];
#pragma unroll
      for (int i = 0; i < 4; i++) {
        int r = wm + lm + i * 16;
        a[i] = *(const bf16x8*)&As[r * 64 + ((ua ^ (r & 7)) * 8)];
      }
#pragma unroll
      for (int j = 0; j < 4; j++) {
        int r = wn + lm + j * 16;
        b[j] = *(const bf16x8*)&Bs[r * 64 + ((ua ^ (r & 7)) * 8)];
      }
#pragma unroll
      for (int i = 0; i < 4; i++)
#pragma unroll
        for (int j = 0; j < 4; j++)
          acc[i][j] = __builtin_amdgcn_mfma_f32_16x16x32_bf16(a[i], b[j], acc[i][j], 0, 0, 0);
    }
    __syncthreads();
  }

  // ---- epilogue ----
  if (POOL && n0 == 0) {
#pragma unroll
    for (int i = 0; i < 4; i++) {
      int sample = (m0 + wm + i * 16) >> 4;
#pragma unroll
      for (int j = 0; j < 4; j++) {
        int col = wn + j * 16 + lm;
        float b = bias[col];
        float s = 0.f;
#pragma unroll
        for (int r = 0; r < 4; r++) s += fmaxf(acc[i][j][r] + b, 0.f);
        s += __shfl_xor(s, 16);
        s += __shfl_xor(s, 32);
        if (quad == 0) pool_out[(size_t)sample * 128 + col] = (bf16)(s * 0.0625f);
      }
    }
  } else if (QFUSE) {
    // write relu'd z2 tile to LDS (128x128 bf16 = 32KB, reuses staging)
#pragma unroll
    for (int i = 0; i < 4; i++)
#pragma unroll
      for (int j = 0; j < 4; j++) {
        int col = wn + j * 16 + lm;
        float b = bias[n0 + col];
#pragma unroll
        for (int r = 0; r < 4; r++) {
          int row = wm + i * 16 + quad * 4 + r;
          smem[row * 128 + col] = (bf16)fmaxf(acc[i][j][r] + b, 0.f);
        }
      }
    __syncthreads();
    // q partial: per row, dot(z2[row, n0:n0+128], W3[n0:n0+128, n])
    int n = lane & 7;
    int kg = lane >> 3;                       // 8 column-groups of 16
    float w3r[16];
#pragma unroll
    for (int i = 0; i < 16; i++) w3r[i] = W3[(size_t)(n0 + kg * 16 + i) * 8 + n];
    int rbase = wave * 32;
    for (int rr = 0; rr < 32; rr++) {
      const bf16* zr = &smem[(rbase + rr) * 128 + kg * 16];
      bf16x8 z0 = *(const bf16x8*)zr;
      bf16x8 z1v = *(const bf16x8*)(zr + 8);
      float s = 0.f;
#pragma unroll
      for (int i = 0; i < 8; i++) s += (float)z0[i] * w3r[i];
#pragma unroll
      for (int i = 0; i < 8; i++) s += (float)z1v[i] * w3r[8 + i];
      s += __shfl_down(s, 32);
      s += __shfl_down(s, 16);
      s += __shfl_down(s, 8);
      if (lane < 8) qpart[((size_t)blockIdx.x * 32768 + m0 + rbase + rr) * 8 + n] = s;
    }
  } else {
    const int coff = POOL ? (n0 - 128) : n0;
#pragma unroll
    for (int i = 0; i < 4; i++)
#pragma unroll
      for (int j = 0; j < 4; j++) {
        int gcol = n0 + wn + j * 16 + lm;
        float b = bias[gcol];
        int col = coff + wn + j * 16 + lm;
#pragma unroll
        for (int r = 0; r < 4; r++) {
          int row = m0 + wm + i * 16 + quad * 4 + r;
          float v = fmaxf(acc[i][j][r] + b, 0.f);
          C[(size_t)row * ldc + col] = (bf16)v;
        }
      }
  }
}

// ---- fused collapsed-GCN chain: xbar -> x2 -> x3 -> g ----
__global__ __launch_bounds__(256) void gcn_chain(
    const bf16* __restrict__ xbar, const bf16* __restrict__ Wg0T,
    const bf16* __restrict__ Wg1T, const bf16* __restrict__ WpostT,
    const float* __restrict__ b_gcn, const float* __restrict__ b_post,
    bf16* __restrict__ g) {
  __shared__ bf16 xs[16 * 136];
  __shared__ bf16 ws[256 * 136];
  const int tid = threadIdx.x;
  const int lane = tid & 63, wave = tid >> 6;
  const int lm = lane & 15, quad = lane >> 4;
  const int rb = blockIdx.x * 16;

  {
    int row = tid >> 4, cv = (tid & 15) * 8;
    *(bf16x8*)&xs[row * 136 + cv] = *(const bf16x8*)&xbar[(size_t)(rb + row) * 128 + cv];
  }

  const bf16* Wl[3] = {Wg0T, Wg1T, WpostT};
  const float* bl[3] = {b_gcn, b_gcn + 128, b_post};
  const int Nl[3] = {128, 128, 256};

  for (int l = 0; l < 3; l++) {
    const int N = Nl[l];
    __syncthreads();
    for (int c = tid; c < N * 16; c += 256) {
      int row = c >> 4, cv = (c & 15) * 8;
      *(bf16x8*)&ws[row * 136 + cv] = *(const bf16x8*)&Wl[l][(size_t)row * 128 + cv];
    }
    __syncthreads();
    const int nj = N / 64;
    f32x4 acc[4] = {};
#pragma unroll
    for (int kk = 0; kk < 128; kk += 32) {
      bf16x8 a = *(const bf16x8*)&xs[lm * 136 + quad * 8 + kk];
      for (int j = 0; j < nj; j++) {
        int col = (wave * nj + j) * 16 + lm;
        bf16x8 b = *(const bf16x8*)&ws[col * 136 + quad * 8 + kk];
        acc[j] = __builtin_amdgcn_mfma_f32_16x16x32_bf16(a, b, acc[j], 0, 0, 0);
      }
    }
    __syncthreads();
    const float* bias = bl[l];
    if (l < 2) {
      for (int j = 0; j < nj; j++) {
        int col = (wave * nj + j) * 16 + lm;
        float bv = bias[col];
#pragma unroll
        for (int r = 0; r < 4; r++)
          xs[(quad * 4 + r) * 136 + col] = (bf16)fmaxf(acc[j][r] + bv, 0.f);
      }
    } else {
      for (int j = 0; j < nj; j++) {
        int col = (wave * nj + j) * 16 + lm;
        float bv = bias[col];
#pragma unroll
        for (int r = 0; r < 4; r++)
          g[(size_t)(rb + quad * 4 + r) * 256 + col] = (bf16)fmaxf(acc[j][r] + bv, 0.f);
      }
    }
  }
}

// ---- final q reduction: q = sum_t qpart[t] + b3 ----
__global__ __launch_bounds__(256) void reduce_q(const float* __restrict__ qpart,
                                                const float* __restrict__ b3,
                                                float* __restrict__ out) {
  int idx = blockIdx.x * 256 + threadIdx.x;      // float4 index, 65536 total
  const float4* qp = (const float4*)qpart;
  float4 s = qp[idx];
  float4 t1 = qp[idx + 65536];
  float4 t2 = qp[idx + 131072];
  float4 t3 = qp[idx + 196608];
  const float4* b = (const float4*)b3;
  float4 bb = b[idx & 1];
  s.x += t1.x + t2.x + t3.x + bb.x;
  s.y += t1.y + t2.y + t3.y + bb.y;
  s.z += t1.z + t2.z + t3.z + bb.z;
  s.w += t1.w + t2.w + t3.w + bb.w;
  ((float4*)out)[idx] = s;
}

extern "C" void kernel_launch(void* const* d_in, const int* in_sizes, int n_in,
                              void* d_out, int out_size, void* d_ws, size_t ws_size,
                              hipStream_t stream) {
  const float* obs    = (const float*)d_in[0];
  const float* W_pre  = (const float*)d_in[1];
  const float* b_pre  = (const float*)d_in[2];
  const float* W_gcn  = (const float*)d_in[3];
  const float* b_gcn  = (const float*)d_in[4];
  const float* W_post = (const float*)d_in[5];
  const float* b_post = (const float*)d_in[6];
  const float* W_loc  = (const float*)d_in[7];
  const float* b_loc  = (const float*)d_in[8];
  const float* W1     = (const float*)d_in[9];
  const float* b1     = (const float*)d_in[10];
  const float* W2     = (const float*)d_in[11];
  const float* b2     = (const float*)d_in[12];
  const float* W3     = (const float*)d_in[13];
  const float* b3     = (const float*)d_in[14];
  float* out = (float*)d_out;

  char* p = (char*)d_ws;
  auto alloc = [&](size_t bytes) { char* r = p; p += (bytes + 255) & ~(size_t)255; return r; };
  bf16* WpreLocT = (bf16*)alloc(384 * 128 * 2);
  float* biasPL  = (float*)alloc(384 * 4);
  bf16* Wg0T   = (bf16*)alloc(128 * 128 * 2);
  bf16* Wg1T   = (bf16*)alloc(128 * 128 * 2);
  bf16* WpostT = (bf16*)alloc(256 * 128 * 2);
  bf16* W1T    = (bf16*)alloc(512 * 512 * 2);
  bf16* W2T    = (bf16*)alloc(512 * 512 * 2);
  bf16* obs_bf = (bf16*)alloc((size_t)32768 * 128 * 2);
  bf16* xbar   = (bf16*)alloc(2048 * 128 * 2);
  bf16* loc    = (bf16*)alloc((size_t)32768 * 256 * 2);
  bf16* g      = (bf16*)alloc(2048 * 256 * 2);
  bf16* z1     = (bf16*)alloc((size_t)32768 * 512 * 2);
  float* qpart = (float*)alloc((size_t)4 * 32768 * 8 * 4);

  // P: all prep in one launch
  prep_all<<<2625, 256, 0, stream>>>(obs, obs_bf, W1, W2, W1T, W2T,
                                     W_pre, W_loc, W_gcn, W_post,
                                     WpreLocT, Wg0T, Wg1T, WpostT,
                                     b_pre, b_loc, biasPL);
  // K1: fused pre (pool -> xbar) + loc
  gemm_k<false, true, false, 3><<<dim3(3, 256), 256, 0, stream>>>(
      obs_bf, nullptr, WpreLocT, biasPL, loc, 256, xbar, nullptr, nullptr, 32768, 128);
  // K2: collapsed GCN chain
  gcn_chain<<<128, 256, 0, stream>>>(xbar, Wg0T, Wg1T, WpostT, b_gcn, b_post, g);
  // K3: z1 = relu([g | loc] @ W1 + b1)
  gemm_k<true, false, false, 4><<<dim3(4, 256), 256, 0, stream>>>(
      loc, g, W1T, b1, z1, 512, nullptr, nullptr, nullptr, 32768, 512);
  // K4: z2 = relu(z1 @ W2 + b2) fused with q-partial (z2 never hits HBM)
  gemm_k<false, false, true, 4><<<dim3(4, 256), 256, 0, stream>>>(
      z1, nullptr, W2T, b2, nullptr, 0, nullptr, W3, qpart, 32768, 512);
  // K5: q = sum of partials + b3
  reduce_q<<<256, 256, 0, stream>>>(qpart, b3, out);
}

// Round 4
// 177.434 us; speedup vs baseline: 1.1978x; 1.0440x over previous
//
#include <hip/hip_runtime.h>
#include <hip/hip_bf16.h>
#include <stdint.h>

typedef __bf16 bf16;
typedef __bf16 bf16x4 __attribute__((ext_vector_type(4)));
typedef __bf16 bf16x8 __attribute__((ext_vector_type(8)));
typedef float f32x4 __attribute__((ext_vector_type(4)));

#define BM 128
#define BN 128
#define BK 64

#define GL(p) ((const __attribute__((address_space(1))) void*)(p))
#define SH(p) ((__attribute__((address_space(3))) void*)(p))

// ---- mega-prep: obs->bf16, tiled W1/W2 transpose, small transposes, bias ----
__device__ inline void tp(const float* W, bf16* WT, int id, int shiftK, int N) {
  int K = 1 << shiftK;
  int n = id >> shiftK;
  int k = id & (K - 1);
  WT[id] = (bf16)W[(size_t)k * N + n];
}

__global__ __launch_bounds__(256) void prep_all(
    const float* __restrict__ obs, bf16* __restrict__ obs_bf,
    const float* __restrict__ W1, const float* __restrict__ W2,
    bf16* __restrict__ W1T, bf16* __restrict__ W2T,
    const float* __restrict__ Wpre, const float* __restrict__ Wloc,
    const float* __restrict__ Wgcn, const float* __restrict__ Wpost,
    bf16* __restrict__ WpreLocT, bf16* __restrict__ Wg0T, bf16* __restrict__ Wg1T,
    bf16* __restrict__ WpostT,
    const float* __restrict__ bpre, const float* __restrict__ bloc,
    float* __restrict__ biasPL) {
  __shared__ bf16 tile[64 * 68];
  int blk = blockIdx.x;
  int tid = threadIdx.x;
  if (blk < 2048) {                      // obs fp32 -> bf16
    int id = blk * 256 + tid;
    const float4* s = (const float4*)(obs + (size_t)id * 8);
    float4 f0 = s[0], f1 = s[1];
    bf16x8 v;
    v[0] = (bf16)f0.x; v[1] = (bf16)f0.y; v[2] = (bf16)f0.z; v[3] = (bf16)f0.w;
    v[4] = (bf16)f1.x; v[5] = (bf16)f1.y; v[6] = (bf16)f1.z; v[7] = (bf16)f1.w;
    *(bf16x8*)(obs_bf + (size_t)id * 8) = v;
    return;
  }
  blk -= 2048;
  if (blk < 128) {                       // tiled transpose W1/W2
    const float* W = (blk < 64) ? W1 : W2;
    bf16* WT = (blk < 64) ? W1T : W2T;
    int t = blk & 63;
    int tk0 = (t >> 3) * 64, tn0 = (t & 7) * 64;
#pragma unroll
    for (int p = 0; p < 4; p++) {
      int kr = p * 16 + (tid >> 4), nc = (tid & 15) * 4;
      float4 f = *(const float4*)(W + (size_t)(tk0 + kr) * 512 + tn0 + nc);
      bf16x4 v; v[0] = (bf16)f.x; v[1] = (bf16)f.y; v[2] = (bf16)f.z; v[3] = (bf16)f.w;
      *(bf16x4*)&tile[kr * 68 + nc] = v;
    }
    __syncthreads();
#pragma unroll
    for (int p = 0; p < 4; p++) {
      int nr = p * 16 + (tid >> 4), kc = (tid & 15) * 4;
      bf16x4 v;
#pragma unroll
      for (int i = 0; i < 4; i++) v[i] = tile[(kc + i) * 68 + nr];
      *(bf16x4*)(WT + (size_t)(tn0 + nr) * 512 + tk0 + kc) = v;
    }
    return;
  }
  blk -= 128;
  if (blk < 448) {                       // small transposes
    int id = blk * 256 + tid;
    if (id < 16384) { tp(Wpre, WpreLocT, id, 7, 128); return; } id -= 16384;
    if (id < 32768) { tp(Wloc, WpreLocT + 16384, id, 7, 256); return; } id -= 32768;
    if (id < 16384) { tp(Wgcn, Wg0T, id, 7, 128); return; } id -= 16384;
    if (id < 16384) { tp(Wgcn + 16384, Wg1T, id, 7, 128); return; } id -= 16384;
    tp(Wpost, WpostT, id, 7, 256);
    return;
  }
  if (tid < 128) biasPL[tid] = bpre[tid];
  biasPL[128 + tid] = bloc[tid];
}

// ---- 128x128 bf16 MFMA GEMM, C = relu(A @ B^T + bias) ----
// XCD-swizzled 1-D grid (256*NT blocks): all NT n-tile siblings of an m-tile
// map to the same XCD (id%8 invariant) so the A-tile is fetched into that
// XCD's L2 once instead of NT times.
// global_load_lds staging (16B/lane), XOR-swizzled source addresses so the
// unpadded LDS layout is conflict-free for ds_read_b128 fragment reads.
// CONCAT: A = [g(repeat16) | loc].  POOL: K1 (n-tile 0 -> pooled xbar only).
// QFUSE: K4 (no C store; z2 tile -> LDS -> q-partial vs W3 n-slice).
template <int NT, bool CONCAT, bool POOL, bool QFUSE>
__global__ __launch_bounds__(256, 4) void gemm_k(
    const bf16* __restrict__ Ab, const bf16* __restrict__ Ag,
    const bf16* __restrict__ BT, const float* __restrict__ bias,
    bf16* __restrict__ C, int ldc, bf16* __restrict__ pool_out,
    const float* __restrict__ W3, float* __restrict__ qpart,
    int M, int K) {
  __shared__ bf16 smem[16384];
  bf16* As = smem;
  bf16* Bs = smem + 8192;

  const int tid = threadIdx.x;
  const int id = blockIdx.x;
  const int s = id >> 3;
  const int n_idx = s % NT;
  const int m0 = ((id & 7) + 8 * (s / NT)) * BM;
  const int n0 = n_idx * BN;

  f32x4 acc[4][4] = {};

  const int lane = tid & 63;
  const int wave = tid >> 6;
  const int wm = (wave >> 1) * 64;
  const int wn = (wave & 1) * 64;
  const int lm = lane & 15;
  const int quad = lane >> 4;

  for (int k0 = 0; k0 < K; k0 += BK) {
#pragma unroll
    for (int it = 0; it < 4; it++) {
      int idx = it * 256 + tid;
      int row = idx >> 3;
      int cv8 = (idx & 7) ^ (row & 7);
      int kk = k0 + cv8 * 8;
      const bf16* ga;
      if (CONCAT) {
        int r = m0 + row;
        ga = (k0 < 256) ? (Ag + (size_t)(r >> 4) * 256 + kk)
                        : (Ab + (size_t)r * 256 + (kk - 256));
      } else {
        ga = Ab + (size_t)(m0 + row) * K + kk;
      }
      const bf16* gb = BT + (size_t)(n0 + row) * K + kk;
      __builtin_amdgcn_global_load_lds(GL(ga), SH(&As[(idx & ~63) * 8]), 16, 0, 0);
      __builtin_amdgcn_global_load_lds(GL(gb), SH(&Bs[(idx & ~63) * 8]), 16, 0, 0);
    }
    __syncthreads();

#pragma unroll
    for (int ks = 0; ks < 2; ks++) {
      const int ua = quad + ks * 4;
      bf16x8 a[4], b[4];
#pragma unroll
      for (int i = 0; i < 4; i++) {
        int r = wm + lm + i * 16;
        a[i] = *(const bf16x8*)&As[r * 64 + ((ua ^ (r & 7)) * 8)];
      }
#pragma unroll
      for (int j = 0; j < 4; j++) {
        int r = wn + lm + j * 16;
        b[j] = *(const bf16x8*)&Bs[r * 64 + ((ua ^ (r & 7)) * 8)];
      }
#pragma unroll
      for (int i = 0; i < 4; i++)
#pragma unroll
        for (int j = 0; j < 4; j++)
          acc[i][j] = __builtin_amdgcn_mfma_f32_16x16x32_bf16(a[i], b[j], acc[i][j], 0, 0, 0);
    }
    __syncthreads();
  }

  // ---- epilogue ----
  if (POOL && n_idx == 0) {
#pragma unroll
    for (int i = 0; i < 4; i++) {
      int sample = (m0 + wm + i * 16) >> 4;
#pragma unroll
      for (int j = 0; j < 4; j++) {
        int col = wn + j * 16 + lm;
        float b = bias[col];
        float v = 0.f;
#pragma unroll
        for (int r = 0; r < 4; r++) v += fmaxf(acc[i][j][r] + b, 0.f);
        v += __shfl_xor(v, 16);
        v += __shfl_xor(v, 32);
        if (quad == 0) pool_out[(size_t)sample * 128 + col] = (bf16)(v * 0.0625f);
      }
    }
  } else if (QFUSE) {
    // z2 tile -> LDS (bf16), then per-row dot with this n-slice of W3
#pragma unroll
    for (int i = 0; i < 4; i++)
#pragma unroll
      for (int j = 0; j < 4; j++) {
        int col = wn + j * 16 + lm;
        float b = bias[n0 + col];
#pragma unroll
        for (int r = 0; r < 4; r++) {
          int row = wm + i * 16 + quad * 4 + r;
          smem[row * 128 + col] = (bf16)fmaxf(acc[i][j][r] + b, 0.f);
        }
      }
    __syncthreads();
    int n = lane & 7;
    int kg = lane >> 3;
    float w3r[16];
#pragma unroll
    for (int i = 0; i < 16; i++) w3r[i] = W3[(size_t)(n0 + kg * 16 + i) * 8 + n];
    int rbase = wave * 32;
    for (int rr = 0; rr < 32; rr++) {
      const bf16* zr = &smem[(rbase + rr) * 128 + kg * 16];
      bf16x8 z0 = *(const bf16x8*)zr;
      bf16x8 z1v = *(const bf16x8*)(zr + 8);
      float v = 0.f;
#pragma unroll
      for (int i = 0; i < 8; i++) v += (float)z0[i] * w3r[i];
#pragma unroll
      for (int i = 0; i < 8; i++) v += (float)z1v[i] * w3r[8 + i];
      v += __shfl_down(v, 32);
      v += __shfl_down(v, 16);
      v += __shfl_down(v, 8);
      if (lane < 8) qpart[((size_t)n_idx * 32768 + m0 + rbase + rr) * 8 + n] = v;
    }
  } else {
    // coalesced store: acc -> LDS bf16 tile -> dwordx4 row stores
#pragma unroll
    for (int i = 0; i < 4; i++)
#pragma unroll
      for (int j = 0; j < 4; j++) {
        int col = wn + j * 16 + lm;
        float b = bias[n0 + col];
#pragma unroll
        for (int r = 0; r < 4; r++) {
          int row = wm + i * 16 + quad * 4 + r;
          smem[row * 128 + col] = (bf16)fmaxf(acc[i][j][r] + b, 0.f);
        }
      }
    __syncthreads();
    const int coff = POOL ? (n0 - 128) : n0;
#pragma unroll
    for (int c = 0; c < 8; c++) {
      int ci = c * 256 + tid;
      int row = ci >> 4, col8 = (ci & 15) * 8;
      *(bf16x8*)&C[(size_t)(m0 + row) * ldc + coff + col8] = *(const bf16x8*)&smem[row * 128 + col8];
    }
  }
}

// ---- fused collapsed-GCN chain: xbar -> x2 -> x3 -> g ----
__global__ __launch_bounds__(256) void gcn_chain(
    const bf16* __restrict__ xbar, const bf16* __restrict__ Wg0T,
    const bf16* __restrict__ Wg1T, const bf16* __restrict__ WpostT,
    const float* __restrict__ b_gcn, const float* __restrict__ b_post,
    bf16* __restrict__ g) {
  __shared__ bf16 xs[16 * 136];
  __shared__ bf16 ws[256 * 136];
  const int tid = threadIdx.x;
  const int lane = tid & 63, wave = tid >> 6;
  const int lm = lane & 15, quad = lane >> 4;
  const int rb = blockIdx.x * 16;

  {
    int row = tid >> 4, cv = (tid & 15) * 8;
    *(bf16x8*)&xs[row * 136 + cv] = *(const bf16x8*)&xbar[(size_t)(rb + row) * 128 + cv];
  }

  const bf16* Wl[3] = {Wg0T, Wg1T, WpostT};
  const float* bl[3] = {b_gcn, b_gcn + 128, b_post};
  const int Nl[3] = {128, 128, 256};

  for (int l = 0; l < 3; l++) {
    const int N = Nl[l];
    __syncthreads();
    for (int c = tid; c < N * 16; c += 256) {
      int row = c >> 4, cv = (c & 15) * 8;
      *(bf16x8*)&ws[row * 136 + cv] = *(const bf16x8*)&Wl[l][(size_t)row * 128 + cv];
    }
    __syncthreads();
    const int nj = N / 64;
    f32x4 acc[4] = {};
#pragma unroll
    for (int kk = 0; kk < 128; kk += 32) {
      bf16x8 a = *(const bf16x8*)&xs[lm * 136 + quad * 8 + kk];
      for (int j = 0; j < nj; j++) {
        int col = (wave * nj + j) * 16 + lm;
        bf16x8 b = *(const bf16x8*)&ws[col * 136 + quad * 8 + kk];
        acc[j] = __builtin_amdgcn_mfma_f32_16x16x32_bf16(a, b, acc[j], 0, 0, 0);
      }
    }
    __syncthreads();
    const float* bias = bl[l];
    if (l < 2) {
      for (int j = 0; j < nj; j++) {
        int col = (wave * nj + j) * 16 + lm;
        float bv = bias[col];
#pragma unroll
        for (int r = 0; r < 4; r++)
          xs[(quad * 4 + r) * 136 + col] = (bf16)fmaxf(acc[j][r] + bv, 0.f);
      }
    } else {
      for (int j = 0; j < nj; j++) {
        int col = (wave * nj + j) * 16 + lm;
        float bv = bias[col];
#pragma unroll
        for (int r = 0; r < 4; r++)
          g[(size_t)(rb + quad * 4 + r) * 256 + col] = (bf16)fmaxf(acc[j][r] + bv, 0.f);
      }
    }
  }
}

// ---- final q reduction ----
__global__ __launch_bounds__(256) void reduce_q(const float* __restrict__ qpart,
                                                const float* __restrict__ b3,
                                                float* __restrict__ out) {
  int idx = blockIdx.x * 256 + threadIdx.x;
  const float4* qp = (const float4*)qpart;
  float4 v = qp[idx];
  float4 t1 = qp[idx + 65536];
  float4 t2 = qp[idx + 131072];
  float4 t3 = qp[idx + 196608];
  const float4* b = (const float4*)b3;
  float4 bb = b[idx & 1];
  v.x += t1.x + t2.x + t3.x + bb.x;
  v.y += t1.y + t2.y + t3.y + bb.y;
  v.z += t1.z + t2.z + t3.z + bb.z;
  v.w += t1.w + t2.w + t3.w + bb.w;
  ((float4*)out)[idx] = v;
}

extern "C" void kernel_launch(void* const* d_in, const int* in_sizes, int n_in,
                              void* d_out, int out_size, void* d_ws, size_t ws_size,
                              hipStream_t stream) {
  const float* obs    = (const float*)d_in[0];
  const float* W_pre  = (const float*)d_in[1];
  const float* b_pre  = (const float*)d_in[2];
  const float* W_gcn  = (const float*)d_in[3];
  const float* b_gcn  = (const float*)d_in[4];
  const float* W_post = (const float*)d_in[5];
  const float* b_post = (const float*)d_in[6];
  const float* W_loc  = (const float*)d_in[7];
  const float* b_loc  = (const float*)d_in[8];
  const float* W1     = (const float*)d_in[9];
  const float* b1     = (const float*)d_in[10];
  const float* W2     = (const float*)d_in[11];
  const float* b2     = (const float*)d_in[12];
  const float* W3     = (const float*)d_in[13];
  const float* b3     = (const float*)d_in[14];
  float* out = (float*)d_out;

  char* p = (char*)d_ws;
  auto alloc = [&](size_t bytes) { char* r = p; p += (bytes + 255) & ~(size_t)255; return r; };
  bf16* WpreLocT = (bf16*)alloc(384 * 128 * 2);
  float* biasPL  = (float*)alloc(384 * 4);
  bf16* Wg0T   = (bf16*)alloc(128 * 128 * 2);
  bf16* Wg1T   = (bf16*)alloc(128 * 128 * 2);
  bf16* WpostT = (bf16*)alloc(256 * 128 * 2);
  bf16* W1T    = (bf16*)alloc(512 * 512 * 2);
  bf16* W2T    = (bf16*)alloc(512 * 512 * 2);
  bf16* obs_bf = (bf16*)alloc((size_t)32768 * 128 * 2);
  bf16* xbar   = (bf16*)alloc(2048 * 128 * 2);
  bf16* loc    = (bf16*)alloc((size_t)32768 * 256 * 2);
  bf16* g      = (bf16*)alloc(2048 * 256 * 2);
  bf16* z1     = (bf16*)alloc((size_t)32768 * 512 * 2);
  float* qpart = (float*)alloc((size_t)4 * 32768 * 8 * 4);

  prep_all<<<2625, 256, 0, stream>>>(obs, obs_bf, W1, W2, W1T, W2T,
                                     W_pre, W_loc, W_gcn, W_post,
                                     WpreLocT, Wg0T, Wg1T, WpostT,
                                     b_pre, b_loc, biasPL);
  // K1: fused pre (pool -> xbar) + loc, XCD-swizzled (3 siblings/m-tile)
  gemm_k<3, false, true, false><<<768, 256, 0, stream>>>(
      obs_bf, nullptr, WpreLocT, biasPL, loc, 256, xbar, nullptr, nullptr, 32768, 128);
  // K2: collapsed GCN chain
  gcn_chain<<<128, 256, 0, stream>>>(xbar, Wg0T, Wg1T, WpostT, b_gcn, b_post, g);
  // K3: z1 = relu([g | loc] @ W1 + b1), XCD-swizzled (4 siblings/m-tile)
  gemm_k<4, true, false, false><<<1024, 256, 0, stream>>>(
      loc, g, W1T, b1, z1, 512, nullptr, nullptr, nullptr, 32768, 512);
  // K4: z2 = relu(z1 @ W2 + b2) fused with q-partial
  gemm_k<4, false, false, true><<<1024, 256, 0, stream>>>(
      z1, nullptr, W2T, b2, nullptr, 0, nullptr, W3, qpart, 32768, 512);
  // K5: q = sum of partials + b3
  reduce_q<<<256, 256, 0, stream>>>(qpart, b3, out);
}

// Round 7
// 174.251 us; speedup vs baseline: 1.2196x; 1.0183x over previous
//
#include <hip/hip_runtime.h>
#include <hip/hip_bf16.h>
#include <stdint.h>

typedef __bf16 bf16;
typedef __bf16 bf16x4 __attribute__((ext_vector_type(4)));
typedef __bf16 bf16x8 __attribute__((ext_vector_type(8)));
typedef float f32x4 __attribute__((ext_vector_type(4)));

#define BM 128
#define BN 128
#define BK 64

#define GL(p) ((const __attribute__((address_space(1))) void*)(p))
#define SH(p) ((__attribute__((address_space(3))) void*)(p))

// ---- prep: W transposes (bf16), bias concat, zero d_out ----
__device__ inline void tp(const float* W, bf16* WT, int id, int shiftK, int N) {
  int K = 1 << shiftK;
  int n = id >> shiftK;
  int k = id & (K - 1);
  WT[id] = (bf16)W[(size_t)k * N + n];
}

__global__ __launch_bounds__(256) void prep_all(
    const float* __restrict__ W1, const float* __restrict__ W2,
    bf16* __restrict__ W1T, bf16* __restrict__ W2T,
    const float* __restrict__ Wpre, const float* __restrict__ Wloc,
    const float* __restrict__ Wgcn, const float* __restrict__ Wpost,
    bf16* __restrict__ WpreLocT, bf16* __restrict__ Wg0T, bf16* __restrict__ Wg1T,
    bf16* __restrict__ WpostT,
    const float* __restrict__ bpre, const float* __restrict__ bloc,
    float* __restrict__ biasPL, float* __restrict__ outq) {
  __shared__ bf16 tile[64 * 68];
  int blk = blockIdx.x;
  int tid = threadIdx.x;
  if (blk < 128) {                       // tiled transpose W1/W2 (512x512 each)
    const float* W = (blk < 64) ? W1 : W2;
    bf16* WT = (blk < 64) ? W1T : W2T;
    int t = blk & 63;
    int tk0 = (t >> 3) * 64, tn0 = (t & 7) * 64;
#pragma unroll
    for (int p = 0; p < 4; p++) {
      int kr = p * 16 + (tid >> 4), nc = (tid & 15) * 4;
      float4 f = *(const float4*)(W + (size_t)(tk0 + kr) * 512 + tn0 + nc);
      bf16x4 v; v[0] = (bf16)f.x; v[1] = (bf16)f.y; v[2] = (bf16)f.z; v[3] = (bf16)f.w;
      *(bf16x4*)&tile[kr * 68 + nc] = v;
    }
    __syncthreads();
#pragma unroll
    for (int p = 0; p < 4; p++) {
      int nr = p * 16 + (tid >> 4), kc = (tid & 15) * 4;
      bf16x4 v;
#pragma unroll
      for (int i = 0; i < 4; i++) v[i] = tile[(kc + i) * 68 + nr];
      *(bf16x4*)(WT + (size_t)(tn0 + nr) * 512 + tk0 + kc) = v;
    }
    return;
  }
  blk -= 128;
  if (blk < 448) {                       // small transposes
    int id = blk * 256 + tid;
    if (id < 16384) { tp(Wpre, WpreLocT, id, 7, 128); return; } id -= 16384;
    if (id < 32768) { tp(Wloc, WpreLocT + 16384, id, 7, 256); return; } id -= 32768;
    if (id < 16384) { tp(Wgcn, Wg0T, id, 7, 128); return; } id -= 16384;
    if (id < 16384) { tp(Wgcn + 16384, Wg1T, id, 7, 128); return; } id -= 16384;
    tp(Wpost, WpostT, id, 7, 256);
    return;
  }
  blk -= 448;
  if (blk == 0) {                        // bias concat
    if (tid < 128) biasPL[tid] = bpre[tid];
    biasPL[128 + tid] = bloc[tid];
    return;
  }
  blk -= 1;
  // zero d_out: 64 blocks x 256 threads x 4 float4 = 65536 float4 = 262144 floats
  float4 z = {0.f, 0.f, 0.f, 0.f};
#pragma unroll
  for (int i = 0; i < 4; i++)
    ((float4*)outq)[(size_t)blk * 1024 + i * 256 + tid] = z;
}

// ---- 128x128 bf16 MFMA GEMM, C = relu(A @ B^T + bias) ----
// XCD-swizzled 1-D grid: all NT n-siblings of an m-tile on one XCD (A in L2 once).
// LDS swizzle invariant (all paths): physical chunk p of row r holds logical
// k-unit p^(r&7). DMA path: load logical c^(r&7) into physical chunk c.
// fp32 path: load logical c^(r&7), ds_write at physical chunk c.  Fragment
// read of logical ua: physical chunk ua^(r&7).
// ASRC: 0 = bf16 [M,K]; 1 = fp32 [M,K]; 2 = virtual concat [g(rep16) | loc].
// POOL: n-tile 0 emits per-sample pooled xbar only. QFUSE: q-head fused, atomic out.
template <int NT, int ASRC, bool POOL, bool QFUSE>
__global__ __launch_bounds__(256, 4) void gemm_k(
    const float* __restrict__ Af, const bf16* __restrict__ Ab, const bf16* __restrict__ Ag,
    const bf16* __restrict__ BT, const float* __restrict__ bias,
    bf16* __restrict__ C, int ldc, bf16* __restrict__ pool_out,
    const float* __restrict__ W3, const float* __restrict__ b3, float* __restrict__ outq,
    int M, int K) {
  __shared__ bf16 smem[16384];
  bf16* As = smem;
  bf16* Bs = smem + 8192;

  const int tid = threadIdx.x;
  const int id = blockIdx.x;
  const int s = id >> 3;
  const int n_idx = s % NT;
  const int m0 = ((id & 7) + 8 * (s / NT)) * BM;
  const int n0 = n_idx * BN;

  f32x4 acc[4][4] = {};

  const int lane = tid & 63;
  const int wave = tid >> 6;
  const int wm = (wave >> 1) * 64;
  const int wn = (wave & 1) * 64;
  const int lm = lane & 15;
  const int quad = lane >> 4;

  for (int k0 = 0; k0 < K; k0 += BK) {
#pragma unroll
    for (int it = 0; it < 4; it++) {
      int idx = it * 256 + tid;
      int row = idx >> 3;
      int c = idx & 7;
      int cv8 = c ^ (row & 7);          // logical k-unit fetched by this thread
      int kk = k0 + cv8 * 8;
      if (ASRC == 1) {
        const float* src = Af + (size_t)(m0 + row) * K + kk;
        float4 f0 = *(const float4*)src;
        float4 f1 = *(const float4*)(src + 4);
        bf16x8 v;
        v[0] = (bf16)f0.x; v[1] = (bf16)f0.y; v[2] = (bf16)f0.z; v[3] = (bf16)f0.w;
        v[4] = (bf16)f1.x; v[5] = (bf16)f1.y; v[6] = (bf16)f1.z; v[7] = (bf16)f1.w;
        *(bf16x8*)&As[row * 64 + c * 8] = v;   // physical chunk c holds logical c^(r&7)
      } else {
        const bf16* ga;
        if (ASRC == 2) {
          int r = m0 + row;
          ga = (k0 < 256) ? (Ag + (size_t)(r >> 4) * 256 + kk)
                          : (Ab + (size_t)r * 256 + (kk - 256));
        } else {
          ga = Ab + (size_t)(m0 + row) * K + kk;
        }
        __builtin_amdgcn_global_load_lds(GL(ga), SH(&As[(idx & ~63) * 8]), 16, 0, 0);
      }
      const bf16* gb = BT + (size_t)(n0 + row) * K + kk;
      __builtin_amdgcn_global_load_lds(GL(gb), SH(&Bs[(idx & ~63) * 8]), 16, 0, 0);
    }
    __syncthreads();

#pragma unroll
    for (int ks = 0; ks < 2; ks++) {
      const int ua = quad + ks * 4;
      bf16x8 a[4], b[4];
#pragma unroll
      for (int i = 0; i < 4; i++) {
        int r = wm + lm + i * 16;
        a[i] = *(const bf16x8*)&As[r * 64 + ((ua ^ (r & 7)) * 8)];
      }
#pragma unroll
      for (int j = 0; j < 4; j++) {
        int r = wn + lm + j * 16;
        b[j] = *(const bf16x8*)&Bs[r * 64 + ((ua ^ (r & 7)) * 8)];
      }
#pragma unroll
      for (int i = 0; i < 4; i++)
#pragma unroll
        for (int j = 0; j < 4; j++)
          acc[i][j] = __builtin_amdgcn_mfma_f32_16x16x32_bf16(a[i], b[j], acc[i][j], 0, 0, 0);
    }
    __syncthreads();
  }

  // ---- epilogue ----
  if (POOL && n_idx == 0) {
#pragma unroll
    for (int i = 0; i < 4; i++) {
      int sample = (m0 + wm + i * 16) >> 4;
#pragma unroll
      for (int j = 0; j < 4; j++) {
        int col = wn + j * 16 + lm;
        float b = bias[col];
        float v = 0.f;
#pragma unroll
        for (int r = 0; r < 4; r++) v += fmaxf(acc[i][j][r] + b, 0.f);
        v += __shfl_xor(v, 16);
        v += __shfl_xor(v, 32);
        if (quad == 0) pool_out[(size_t)sample * 128 + col] = (bf16)(v * 0.0625f);
      }
    }
  } else if (QFUSE) {
    // z2 tile -> LDS, per-row dot with this n-slice of W3, atomic accumulate
#pragma unroll
    for (int i = 0; i < 4; i++)
#pragma unroll
      for (int j = 0; j < 4; j++) {
        int col = wn + j * 16 + lm;
        float b = bias[n0 + col];
#pragma unroll
        for (int r = 0; r < 4; r++) {
          int row = wm + i * 16 + quad * 4 + r;
          smem[row * 128 + col] = (bf16)fmaxf(acc[i][j][r] + b, 0.f);
        }
      }
    __syncthreads();
    int n = lane & 7;
    int kg = lane >> 3;
    float w3r[16];
#pragma unroll
    for (int i = 0; i < 16; i++) w3r[i] = W3[(size_t)(n0 + kg * 16 + i) * 8 + n];
    float bn = (n_idx == 0) ? b3[n] : 0.f;
    int rbase = wave * 32;
    for (int rr = 0; rr < 32; rr++) {
      const bf16* zr = &smem[(rbase + rr) * 128 + kg * 16];
      bf16x8 z0 = *(const bf16x8*)zr;
      bf16x8 z1v = *(const bf16x8*)(zr + 8);
      float v = 0.f;
#pragma unroll
      for (int i = 0; i < 8; i++) v += (float)z0[i] * w3r[i];
#pragma unroll
      for (int i = 0; i < 8; i++) v += (float)z1v[i] * w3r[8 + i];
      v += __shfl_down(v, 32);
      v += __shfl_down(v, 16);
      v += __shfl_down(v, 8);
      if (lane < 8) atomicAdd(&outq[(size_t)(m0 + rbase + rr) * 8 + n], v + bn);
    }
  } else {
    // coalesced store via LDS bf16 tile
#pragma unroll
    for (int i = 0; i < 4; i++)
#pragma unroll
      for (int j = 0; j < 4; j++) {
        int col = wn + j * 16 + lm;
        float b = bias[n0 + col];
#pragma unroll
        for (int r = 0; r < 4; r++) {
          int row = wm + i * 16 + quad * 4 + r;
          smem[row * 128 + col] = (bf16)fmaxf(acc[i][j][r] + b, 0.f);
        }
      }
    __syncthreads();
    const int coff = POOL ? (n0 - 128) : n0;
#pragma unroll
    for (int c = 0; c < 8; c++) {
      int ci = c * 256 + tid;
      int row = ci >> 4, col8 = (ci & 15) * 8;
      *(bf16x8*)&C[(size_t)(m0 + row) * ldc + coff + col8] = *(const bf16x8*)&smem[row * 128 + col8];
    }
  }
}

// ---- fused collapsed-GCN chain: xbar -> x2 -> x3 -> g ----
__global__ __launch_bounds__(256) void gcn_chain(
    const bf16* __restrict__ xbar, const bf16* __restrict__ Wg0T,
    const bf16* __restrict__ Wg1T, const bf16* __restrict__ WpostT,
    const float* __restrict__ b_gcn, const float* __restrict__ b_post,
    bf16* __restrict__ g) {
  __shared__ bf16 xs[16 * 136];
  __shared__ bf16 ws[256 * 136];
  const int tid = threadIdx.x;
  const int lane = tid & 63, wave = tid >> 6;
  const int lm = lane & 15, quad = lane >> 4;
  const int rb = blockIdx.x * 16;

  {
    int row = tid >> 4, cv = (tid & 15) * 8;
    *(bf16x8*)&xs[row * 136 + cv] = *(const bf16x8*)&xbar[(size_t)(rb + row) * 128 + cv];
  }

  const bf16* Wl[3] = {Wg0T, Wg1T, WpostT};
  const float* bl[3] = {b_gcn, b_gcn + 128, b_post};
  const int Nl[3] = {128, 128, 256};

  for (int l = 0; l < 3; l++) {
    const int N = Nl[l];
    __syncthreads();
    for (int c = tid; c < N * 16; c += 256) {
      int row = c >> 4, cv = (c & 15) * 8;
      *(bf16x8*)&ws[row * 136 + cv] = *(const bf16x8*)&Wl[l][(size_t)row * 128 + cv];
    }
    __syncthreads();
    const int nj = N / 64;
    f32x4 acc[4] = {};
#pragma unroll
    for (int kk = 0; kk < 128; kk += 32) {
      bf16x8 a = *(const bf16x8*)&xs[lm * 136 + quad * 8 + kk];
      for (int j = 0; j < nj; j++) {
        int col = (wave * nj + j) * 16 + lm;
        bf16x8 b = *(const bf16x8*)&ws[col * 136 + quad * 8 + kk];
        acc[j] = __builtin_amdgcn_mfma_f32_16x16x32_bf16(a, b, acc[j], 0, 0, 0);
      }
    }
    __syncthreads();
    const float* bias = bl[l];
    if (l < 2) {
      for (int j = 0; j < nj; j++) {
        int col = (wave * nj + j) * 16 + lm;
        float bv = bias[col];
#pragma unroll
        for (int r = 0; r < 4; r++)
          xs[(quad * 4 + r) * 136 + col] = (bf16)fmaxf(acc[j][r] + bv, 0.f);
      }
    } else {
      for (int j = 0; j < nj; j++) {
        int col = (wave * nj + j) * 16 + lm;
        float bv = bias[col];
#pragma unroll
        for (int r = 0; r < 4; r++)
          g[(size_t)(rb + quad * 4 + r) * 256 + col] = (bf16)fmaxf(acc[j][r] + bv, 0.f);
      }
    }
  }
}

extern "C" void kernel_launch(void* const* d_in, const int* in_sizes, int n_in,
                              void* d_out, int out_size, void* d_ws, size_t ws_size,
                              hipStream_t stream) {
  const float* obs    = (const float*)d_in[0];
  const float* W_pre  = (const float*)d_in[1];
  const float* b_pre  = (const float*)d_in[2];
  const float* W_gcn  = (const float*)d_in[3];
  const float* b_gcn  = (const float*)d_in[4];
  const float* W_post = (const float*)d_in[5];
  const float* b_post = (const float*)d_in[6];
  const float* W_loc  = (const float*)d_in[7];
  const float* b_loc  = (const float*)d_in[8];
  const float* W1     = (const float*)d_in[9];
  const float* b1     = (const float*)d_in[10];
  const float* W2     = (const float*)d_in[11];
  const float* b2     = (const float*)d_in[12];
  const float* W3     = (const float*)d_in[13];
  const float* b3     = (const float*)d_in[14];
  float* out = (float*)d_out;

  char* p = (char*)d_ws;
  auto alloc = [&](size_t bytes) { char* r = p; p += (bytes + 255) & ~(size_t)255; return r; };
  bf16* WpreLocT = (bf16*)alloc(384 * 128 * 2);
  float* biasPL  = (float*)alloc(384 * 4);
  bf16* Wg0T   = (bf16*)alloc(128 * 128 * 2);
  bf16* Wg1T   = (bf16*)alloc(128 * 128 * 2);
  bf16* WpostT = (bf16*)alloc(256 * 128 * 2);
  bf16* W1T    = (bf16*)alloc(512 * 512 * 2);
  bf16* W2T    = (bf16*)alloc(512 * 512 * 2);
  bf16* xbar   = (bf16*)alloc(2048 * 128 * 2);
  bf16* loc    = (bf16*)alloc((size_t)32768 * 256 * 2);
  bf16* g      = (bf16*)alloc(2048 * 256 * 2);
  bf16* z1     = (bf16*)alloc((size_t)32768 * 512 * 2);

  // P: weight prep + bias + d_out zero (641 blocks)
  prep_all<<<641, 256, 0, stream>>>(W1, W2, W1T, W2T,
                                    W_pre, W_loc, W_gcn, W_post,
                                    WpreLocT, Wg0T, Wg1T, WpostT,
                                    b_pre, b_loc, biasPL, out);
  // K1: fused pre (pool -> xbar) + loc, A staged directly from fp32 obs
  gemm_k<3, 1, true, false><<<768, 256, 0, stream>>>(
      obs, nullptr, nullptr, WpreLocT, biasPL, loc, 256, xbar,
      nullptr, nullptr, nullptr, 32768, 128);
  // K2: collapsed GCN chain
  gcn_chain<<<128, 256, 0, stream>>>(xbar, Wg0T, Wg1T, WpostT, b_gcn, b_post, g);
  // K3: z1 = relu([g | loc] @ W1 + b1)
  gemm_k<4, 2, false, false><<<1024, 256, 0, stream>>>(
      nullptr, loc, g, W1T, b1, z1, 512, nullptr,
      nullptr, nullptr, nullptr, 32768, 512);
  // K4: z2 = relu(z1 @ W2 + b2) fused with q-head, atomic accumulate into out
  gemm_k<4, 0, false, true><<<1024, 256, 0, stream>>>(
      nullptr, z1, nullptr, W2T, b2, nullptr, 0, nullptr,
      W3, b3, out, 32768, 512);
}